// Round 9
// baseline (163.739 us; speedup 1.0000x reference)
//
#include <hip/hip_runtime.h>
#include <hip/hip_bf16.h>
#include <cstdint>
#include <cstddef>

// B=16 images, 4 scales, pooled 7x7=49 spatial, rows padded to 56 (MROWS=896).
// R9 = R6 anchor (132us) + (1) e-fastest Vb writes w/ recompute (no extra LDS),
//      (2) bijective XCD-chunked block swizzle on all kernels, np={1,2,2,4}.

typedef __attribute__((ext_vector_type(8))) short s16x8;
typedef __attribute__((ext_vector_type(4))) float f32x4;
typedef __attribute__((ext_vector_type(4))) uint32_t u32x4;

#define SPART 802816   // 896*896

__device__ __forceinline__ unsigned short f2bf(float x) {
    uint32_t u = __float_as_uint(x);
    uint32_t r = (u + 0x7fff + ((u >> 16) & 1)) >> 16;
    return (unsigned short)r;
}
__device__ __forceinline__ float bf2f(unsigned short b) {
    return __uint_as_float(((uint32_t)b) << 16);
}
__device__ __forceinline__ void gll16(const void* g, void* l) {
    __builtin_amdgcn_global_load_lds(
        (const __attribute__((address_space(1))) uint32_t*)g,
        (__attribute__((address_space(3))) uint32_t*)l, 16, 0, 0);
}
// bijective XCD-chunk swizzle: consecutive work-ids land on one XCD (m204 variant)
__device__ __forceinline__ int xcd_swz(int b, int nwg) {
    const int q = nwg >> 3, r = nwg & 7;
    const int x = b & 7, t = b >> 3;
    return (x < r ? x * (q + 1) : r * (q + 1) + (x - r) * q) + t;
}

struct PoolParams {
    const float* act[4];
    unsigned short* Pk[4];
    unsigned short* Vb[4];
    int C[4], H[4], k[4], G[4], cum[5];
};

__global__ __launch_bounds__(256) void pool_all_kernel(PoolParams pp) {
    __shared__ alignas(16) float plane[3136];
    int b = xcd_swz(blockIdx.x, pp.cum[4]), s = 0;
    while (b >= pp.cum[s + 1]) s++;
    const int rem = b - pp.cum[s];
    const int C = pp.C[s], H = pp.H[s], k = pp.k[s], G = pp.G[s];
    const int HW = H * H;
    const int nblk_c = C / G;
    const int i  = rem / nblk_c;
    const int c0 = (rem % nblk_c) * G;
    unsigned short* __restrict__ Pk = pp.Pk[s];
    unsigned short* __restrict__ Vb = pp.Vb[s];

    const float4* src4 = reinterpret_cast<const float4*>(pp.act[s] + ((size_t)i * C + c0) * HW);
    float4* plane4 = reinterpret_cast<float4*>(plane);
    for (int idx = threadIdx.x; idx < (G * HW) >> 2; idx += 256)
        plane4[idx] = src4[idx];
    __syncthreads();

    // Pk writes: c-fastest (16B per c-quad)
    for (int idx = threadIdx.x; idx < G * 49; idx += 256) {
        const int e = idx / G, g = idx % G;
        const int eh = e / 7, ew = e % 7;
        const float* ppl = plane + g * HW + (eh * k) * H + ew * k;
        float m = -INFINITY;
        for (int dy = 0; dy < k; ++dy)
            for (int dx = 0; dx < k; ++dx)
                m = fmaxf(m, ppl[dy * H + dx]);
        const int c = c0 + g;
        const unsigned short hb = f2bf(m);
        const unsigned short lb = f2bf(m - bf2f(hb));
        const size_t pk = (((size_t)(c >> 2) * 896) + (size_t)i * 56 + e) * 8 + ((c & 3) * 2);
        *reinterpret_cast<uint32_t*>(&Pk[pk]) = (uint32_t)hb | ((uint32_t)lb << 16);
    }
    // Pk pad rows e=49..55 -> zero
    for (int idx = threadIdx.x; idx < 7 * G; idx += 256) {
        const int e = 49 + idx / G, g = idx % G, c = c0 + g;
        const size_t pk = (((size_t)(c >> 2) * 896) + (size_t)i * 56 + e) * 8 + ((c & 3) * 2);
        *reinterpret_cast<uint32_t*>(&Pk[pk]) = 0;
    }
    // Vb writes: e-fastest (8 consecutive lanes = 16B contiguous); max recomputed
    // (identical fmax order -> bit-identical); covers pad e=49..63 with 0.
    for (int idx = threadIdx.x; idx < (G << 6); idx += 256) {
        const int g = idx >> 6, e = idx & 63, c = c0 + g;
        float m = 0.f;
        if (e < 49) {
            const int eh = e / 7, ew = e % 7;
            const float* ppl = plane + g * HW + (eh * k) * H + ew * k;
            m = -INFINITY;
            for (int dy = 0; dy < k; ++dy)
                for (int dx = 0; dx < k; ++dx)
                    m = fmaxf(m, ppl[dy * H + dx]);
        }
        const size_t vb = (((size_t)i * 8 + (e >> 3)) * C + c) * 8 + (e & 7);
        Vb[vb] = f2bf(m);
    }
}

struct GramParams {
    const unsigned short* Pk[4];
    float* S[4];
    int Kblk[4];   // k' elements per block per pass (=2C/np)
    int cum[5];
};

__global__ __launch_bounds__(256) void gram_kernel(GramParams g) {
    __shared__ short lsA[2][4096];
    __shared__ short lsB[2][4096];
    int b = xcd_swz(blockIdx.x, g.cum[4]), s = 0;
    while (b >= g.cum[s + 1]) s++;
    const int rem = b - g.cum[s];
    const int p = rem / 49, t = rem % 49;
    const int bi = t / 7, bj = t % 7;
    const int Kb = g.Kblk[s];
    const int kg0 = p * (Kb >> 3);
    const unsigned short* __restrict__ Pk = g.Pk[s];
    float* __restrict__ S = g.S[s] + (size_t)p * SPART;

    const int tid = threadIdx.x, lane = tid & 63, w = tid >> 6;
    const int wm = (w >> 1) * 64, wn = (w & 1) * 64;

    f32x4 acc[4][4];
    #pragma unroll
    for (int u = 0; u < 4; ++u)
        #pragma unroll
        for (int v = 0; v < 4; ++v)
            acc[u][v] = (f32x4){0.f, 0.f, 0.f, 0.f};

    const int half = lane >> 4, r16 = lane & 15;
    const int nt = Kb >> 5;

#define GSTAGE(buf, it) do {                                                        \
        const int kq_ = kg0 + (it) * 4 + w;                                         \
        const char* ga_ = (const char*)Pk + ((size_t)kq_ * 896 + bi * 128) * 16 + lane * 16; \
        const char* gb_ = (const char*)Pk + ((size_t)kq_ * 896 + bj * 128) * 16 + lane * 16; \
        gll16(ga_,        (char*)lsA[buf] + w * 2048);                              \
        gll16(ga_ + 1024, (char*)lsA[buf] + w * 2048 + 1024);                       \
        gll16(gb_,        (char*)lsB[buf] + w * 2048);                              \
        gll16(gb_ + 1024, (char*)lsB[buf] + w * 2048 + 1024);                       \
    } while (0)

    GSTAGE(0, 0);
    asm volatile("s_waitcnt vmcnt(0)" ::: "memory");
    __builtin_amdgcn_s_barrier();

    int cur = 0;
    for (int it = 0; it < nt; ++it) {
        if (it + 1 < nt) GSTAGE(cur ^ 1, it + 1);   // prefetch under compute
        s16x8 av[4], bv[4], cv[4];
        #pragma unroll
        for (int u = 0; u < 4; ++u) {
            av[u] = *reinterpret_cast<const s16x8*>(&lsA[cur][((half * 128) + wm + 16 * u + r16) * 8]);
            union { u32x4 u4; s16x8 s8; } ub, uc;
            ub.u4 = *reinterpret_cast<const u32x4*>(&lsB[cur][((half * 128) + wn + 16 * u + r16) * 8]);
            uc.u4 = (ub.u4 >> 16) | (ub.u4 << 16);   // [hi,lo] -> [lo,hi] per dword
            bv[u] = ub.s8;
            cv[u] = uc.s8;
        }
        #pragma unroll
        for (int u = 0; u < 4; ++u)
            #pragma unroll
            for (int v = 0; v < 4; ++v) {
                acc[u][v] = __builtin_amdgcn_mfma_f32_16x16x32_bf16(av[u], bv[v], acc[u][v], 0, 0, 0);
                acc[u][v] = __builtin_amdgcn_mfma_f32_16x16x32_bf16(av[u], cv[v], acc[u][v], 0, 0, 0);
            }
        __builtin_amdgcn_sched_barrier(0);
        asm volatile("s_waitcnt vmcnt(0)" ::: "memory");
        __builtin_amdgcn_s_barrier();
        cur ^= 1;
    }
#undef GSTAGE

    const int rowb = bi * 128 + wm + (lane >> 4) * 4;
    const int colb = bj * 128 + wn + (lane & 15);
    #pragma unroll
    for (int u = 0; u < 4; ++u)
        #pragma unroll
        for (int v = 0; v < 4; ++v)
            #pragma unroll
            for (int rg = 0; rg < 4; ++rg)
                S[(size_t)(rowb + 16 * u + rg) * 896 + colb + 16 * v] = acc[u][v][rg];
}

struct SoftParams {
    const float* S[4];
    float* heat[4];
    unsigned short* Hb[4];
    int np[4];
};

__global__ __launch_bounds__(256) void softmax_kernel(SoftParams sp) {
    const int sb = xcd_swz(blockIdx.x, 3136);
    const int grp = (sb * 256 + threadIdx.x) >> 4;
    const int l = threadIdx.x & 15;
    const int s = grp / 12544;
    const int rem = grp % 12544;
    const int i = rem / 784;
    const int j = (rem / 49) % 16;
    const int e = rem % 49;
    const float* __restrict__ Sb = sp.S[s];
    const int np = sp.np[s];
    const size_t rowoff = ((size_t)(i * 56 + e)) * 896 + j * 56;

    float v[4];
    #pragma unroll
    for (int t = 0; t < 4; ++t) {
        const int f = l + t * 16;
        float x = -INFINITY;
        if (f < 49) {
            x = 0.f;
            for (int p = 0; p < np; ++p) x += Sb[(size_t)p * SPART + rowoff + f];
        }
        v[t] = x;
    }
    float m = fmaxf(fmaxf(v[0], v[1]), fmaxf(v[2], v[3]));
    #pragma unroll
    for (int d = 1; d < 16; d <<= 1) m = fmaxf(m, __shfl_xor(m, d, 16));
    float ex[4], sum = 0.f;
    #pragma unroll
    for (int t = 0; t < 4; ++t) {
        const int f = l + t * 16;
        ex[t] = (f < 49) ? __expf(v[t] - m) : 0.f;
        sum += ex[t];
    }
    #pragma unroll
    for (int d = 1; d < 16; d <<= 1) sum += __shfl_xor(sum, d, 16);
    const float inv = 1.f / sum;

    float* hrow = sp.heat[s] + (((size_t)(i * 16 + j)) * 49 + e) * 49;
    unsigned short* __restrict__ Hb = sp.Hb[s];
    const size_t hbrow = (size_t)i * 56 + e;
    #pragma unroll
    for (int t = 0; t < 4; ++t) {
        const int f = l + t * 16;
        const float hv = (f < 49) ? ex[t] * inv : 0.f;
        if (f < 49) hrow[f] = hv;
        Hb[(((size_t)j * 8 + (f >> 3)) * 896 + hbrow) * 8 + (f & 7)] = f2bf(hv);
    }
}

struct PvParams {
    const unsigned short* Hb[4];
    const unsigned short* Vb[4];
    float* out[4];
    int C[4];
    int cum[5];
};

__global__ __launch_bounds__(256) void pv_kernel(PvParams pv) {
    __shared__ short lsA[8 * 128 * 8];   // Hb tile 16KB
    __shared__ short lsB[8 * 128 * 8];   // Vb tile 16KB
    int b = xcd_swz(blockIdx.x, pv.cum[4]), s = 0;
    while (b >= pv.cum[s + 1]) s++;
    int rem = b - pv.cum[s];
    const int C = pv.C[s], nct = C >> 7;
    const int j = rem / (7 * nct); rem %= 7 * nct;
    const int rt = rem / nct, ct = rem % nct;   // ct-consecutive share (j,rt) Hb tile -> same-XCD L2 hits
    const int tid = threadIdx.x, lane = tid & 63, w = tid >> 6;
    const int wm = (w >> 1) * 64, wn = (w & 1) * 64;
    const unsigned short* __restrict__ Hb = pv.Hb[s];
    const unsigned short* __restrict__ Vb = pv.Vb[s];

    #pragma unroll
    for (int q = 0; q < 2; ++q) {
        const int kq = w + q * 4;
        const char* ga = (const char*)Hb + ((size_t)(j * 8 + kq) * 896 + rt * 128) * 16 + lane * 16;
        const char* gb = (const char*)Vb + ((size_t)(j * 8 + kq) * C + ct * 128) * 16 + lane * 16;
        gll16(ga,        (char*)lsA + kq * 2048);
        gll16(ga + 1024, (char*)lsA + kq * 2048 + 1024);
        gll16(gb,        (char*)lsB + kq * 2048);
        gll16(gb + 1024, (char*)lsB + kq * 2048 + 1024);
    }
    __syncthreads();   // single drain per block; no prior stores pending

    f32x4 acc[4][4];
    #pragma unroll
    for (int u = 0; u < 4; ++u)
        #pragma unroll
        for (int v = 0; v < 4; ++v)
            acc[u][v] = (f32x4){0.f, 0.f, 0.f, 0.f};

    const int r16 = lane & 15;
    #pragma unroll
    for (int ks = 0; ks < 2; ++ks) {
        const int half = ks * 4 + (lane >> 4);
        s16x8 av[4], bv[4];
        #pragma unroll
        for (int u = 0; u < 4; ++u) {
            av[u] = *reinterpret_cast<const s16x8*>(&lsA[((half * 128) + wm + 16 * u + r16) * 8]);
            bv[u] = *reinterpret_cast<const s16x8*>(&lsB[((half * 128) + wn + 16 * u + r16) * 8]);
        }
        #pragma unroll
        for (int u = 0; u < 4; ++u)
            #pragma unroll
            for (int v = 0; v < 4; ++v)
                acc[u][v] = __builtin_amdgcn_mfma_f32_16x16x32_bf16(av[u], bv[v], acc[u][v], 0, 0, 0);
    }

    #pragma unroll
    for (int u = 0; u < 4; ++u) {
        const int mb = rt * 128 + wm + 16 * u + (lane >> 4) * 4;
        #pragma unroll
        for (int rg = 0; rg < 4; ++rg) {
            const int mm = mb + rg;
            const int ii = mm / 56, e = mm % 56;
            if (e < 49) {
                float* orow = pv.out[s] + (((size_t)(ii * 16 + j)) * 49 + e) * C + ct * 128 + (lane & 15);
                #pragma unroll
                for (int v = 0; v < 4; ++v)
                    orow[wn + 16 * v] = acc[u][v][rg];
            }
        }
    }
    // stores drain asynchronously; kernel-end waits once
}

extern "C" void kernel_launch(void* const* d_in, const int* in_sizes, int n_in,
                              void* d_out, int out_size, void* d_ws, size_t ws_size,
                              hipStream_t stream) {
    const int Cs[4] = {256, 512, 1024, 2048};
    const int Hs[4] = {56, 28, 14, 7};
    const int ks[4] = {8, 4, 2, 1};
    const int Gs[4] = {1, 4, 16, 64};

    char* w0 = (char*)d_ws;
    size_t off = 0;
    unsigned short *Pk[4], *Vb[4], *Hb[4];
    for (int s = 0; s < 4; ++s) { Pk[s] = (unsigned short*)(w0 + off); off += (size_t)3584 * Cs[s]; }
    for (int s = 0; s < 4; ++s) { Vb[s] = (unsigned short*)(w0 + off); off += (size_t)2048 * Cs[s]; }
    for (int s = 0; s < 4; ++s) { Hb[s] = (unsigned short*)(w0 + off); off += (size_t)1835008; }

    int np[4] = {1, 2, 2, 4};
    {
        size_t need = off;
        for (int s = 0; s < 4; ++s) need += (size_t)np[s] * SPART * 4;
        if (ws_size < need) { np[0] = np[1] = np[2] = np[3] = 1; }
    }
    float* Sp[4];
    for (int s = 0; s < 4; ++s) { Sp[s] = (float*)(w0 + off); off += (size_t)np[s] * SPART * 4; }

    float* out = (float*)d_out;
    const size_t o1 = 0;
    const size_t o2 = o1 + (size_t)256 * 49 * 256;
    const size_t o3 = o2 + (size_t)256 * 49 * 512;
    const size_t o4 = o3 + (size_t)256 * 49 * 1024;
    const size_t h1 = o4 + (size_t)256 * 49 * 2048;
    const size_t h2 = h1 + (size_t)256 * 2401;
    const size_t h3 = h2 + (size_t)256 * 2401;
    const size_t h4 = h3 + (size_t)256 * 2401;
    float* heat[4] = {out + h1, out + h2, out + h3, out + h4};
    float* outs[4] = {out + o1, out + o2, out + o3, out + o4};

    PoolParams pp;
    pp.cum[0] = 0;
    for (int s = 0; s < 4; ++s) {
        pp.act[s] = (const float*)d_in[s];
        pp.Pk[s] = Pk[s]; pp.Vb[s] = Vb[s];
        pp.C[s] = Cs[s]; pp.H[s] = Hs[s]; pp.k[s] = ks[s]; pp.G[s] = Gs[s];
        pp.cum[s + 1] = pp.cum[s] + 16 * (Cs[s] / Gs[s]);
    }
    pool_all_kernel<<<pp.cum[4], 256, 0, stream>>>(pp);

    GramParams g;
    g.cum[0] = 0;
    for (int s = 0; s < 4; ++s) {
        g.Pk[s] = Pk[s];
        g.S[s] = Sp[s];
        g.Kblk[s] = 2 * Cs[s] / np[s];
        g.cum[s + 1] = g.cum[s] + np[s] * 49;
    }
    gram_kernel<<<g.cum[4], 256, 0, stream>>>(g);

    SoftParams sp;
    for (int s = 0; s < 4; ++s) {
        sp.S[s] = Sp[s]; sp.heat[s] = heat[s]; sp.Hb[s] = Hb[s]; sp.np[s] = np[s];
    }
    softmax_kernel<<<3136, 256, 0, stream>>>(sp);

    PvParams pv;
    pv.cum[0] = 0;
    for (int s = 0; s < 4; ++s) {
        pv.Hb[s] = Hb[s]; pv.Vb[s] = Vb[s]; pv.out[s] = outs[s]; pv.C[s] = Cs[s];
        pv.cum[s + 1] = pv.cum[s] + 16 * 7 * (Cs[s] >> 7);
    }
    pv_kernel<<<pv.cum[4], 256, 0, stream>>>(pv);
}

// Round 10
// 140.830 us; speedup vs baseline: 1.1627x; 1.1627x over previous
//
#include <hip/hip_runtime.h>
#include <hip/hip_bf16.h>
#include <cstdint>
#include <cstddef>

// B=16 images, 4 scales, pooled 7x7=49 spatial, rows padded to 56 (MROWS=896).
// R10 = R6 anchor (132us) byte-identical + XCD-chunk swizzle on pv ONLY
//       (pv work is uniform; gram/pool swizzle caused per-XCD imbalance in R9).

typedef __attribute__((ext_vector_type(8))) short s16x8;
typedef __attribute__((ext_vector_type(4))) float f32x4;
typedef __attribute__((ext_vector_type(4))) uint32_t u32x4;

#define SPART 802816   // 896*896

__device__ __forceinline__ unsigned short f2bf(float x) {
    uint32_t u = __float_as_uint(x);
    uint32_t r = (u + 0x7fff + ((u >> 16) & 1)) >> 16;
    return (unsigned short)r;
}
__device__ __forceinline__ float bf2f(unsigned short b) {
    return __uint_as_float(((uint32_t)b) << 16);
}
__device__ __forceinline__ void gll16(const void* g, void* l) {
    __builtin_amdgcn_global_load_lds(
        (const __attribute__((address_space(1))) uint32_t*)g,
        (__attribute__((address_space(3))) uint32_t*)l, 16, 0, 0);
}
// bijective XCD-chunk swizzle (m204): consecutive work-ids -> one XCD.
// ONLY safe for uniform-duration blocks.
__device__ __forceinline__ int xcd_swz(int b, int nwg) {
    const int q = nwg >> 3, r = nwg & 7;
    const int x = b & 7, t = b >> 3;
    return (x < r ? x * (q + 1) : r * (q + 1) + (x - r) * q) + t;
}

struct PoolParams {
    const float* act[4];
    unsigned short* Pk[4];
    unsigned short* Vb[4];
    int C[4], H[4], k[4], G[4], cum[5];
};

__global__ __launch_bounds__(256) void pool_all_kernel(PoolParams pp) {
    __shared__ alignas(16) float plane[3136];
    int b = blockIdx.x, s = 0;
    while (b >= pp.cum[s + 1]) s++;
    const int rem = b - pp.cum[s];
    const int C = pp.C[s], H = pp.H[s], k = pp.k[s], G = pp.G[s];
    const int HW = H * H;
    const int nblk_c = C / G;
    const int i  = rem / nblk_c;
    const int c0 = (rem % nblk_c) * G;
    unsigned short* __restrict__ Pk = pp.Pk[s];
    unsigned short* __restrict__ Vb = pp.Vb[s];

    const float4* src4 = reinterpret_cast<const float4*>(pp.act[s] + ((size_t)i * C + c0) * HW);
    float4* plane4 = reinterpret_cast<float4*>(plane);
    for (int idx = threadIdx.x; idx < (G * HW) >> 2; idx += 256)
        plane4[idx] = src4[idx];
    __syncthreads();
    for (int idx = threadIdx.x; idx < G * 49; idx += 256) {
        const int e = idx / G, g = idx % G;
        const int eh = e / 7, ew = e % 7;
        const float* ppl = plane + g * HW + (eh * k) * H + ew * k;
        float m = -INFINITY;
        for (int dy = 0; dy < k; ++dy)
            for (int dx = 0; dx < k; ++dx)
                m = fmaxf(m, ppl[dy * H + dx]);
        const int c = c0 + g;
        const unsigned short hb = f2bf(m);
        const unsigned short lb = f2bf(m - bf2f(hb));
        const size_t pk = (((size_t)(c >> 2) * 896) + (size_t)i * 56 + e) * 8 + ((c & 3) * 2);
        *reinterpret_cast<uint32_t*>(&Pk[pk]) = (uint32_t)hb | ((uint32_t)lb << 16);
        const size_t vb = (((size_t)i * 8 + (e >> 3)) * C + c) * 8 + (e & 7);
        Vb[vb] = hb;
    }
    for (int idx = threadIdx.x; idx < 7 * G; idx += 256) {
        const int e = 49 + idx / G, g = idx % G, c = c0 + g;
        const size_t pk = (((size_t)(c >> 2) * 896) + (size_t)i * 56 + e) * 8 + ((c & 3) * 2);
        *reinterpret_cast<uint32_t*>(&Pk[pk]) = 0;
    }
    for (int idx = threadIdx.x; idx < 15 * G; idx += 256) {
        const int e = 49 + idx / G, g = idx % G, c = c0 + g;
        const size_t vb = (((size_t)i * 8 + (e >> 3)) * C + c) * 8 + (e & 7);
        Vb[vb] = 0;
    }
}

struct GramParams {
    const unsigned short* Pk[4];
    float* S[4];
    int Kblk[4];   // k' elements per block per pass (=2C/np)
    int cum[5];
};

__global__ __launch_bounds__(256) void gram_kernel(GramParams g) {
    __shared__ short lsA[2][4096];
    __shared__ short lsB[2][4096];
    int b = blockIdx.x, s = 0;
    while (b >= g.cum[s + 1]) s++;
    const int rem = b - g.cum[s];
    const int p = rem / 49, t = rem % 49;
    const int bi = t / 7, bj = t % 7;
    const int Kb = g.Kblk[s];
    const int kg0 = p * (Kb >> 3);
    const unsigned short* __restrict__ Pk = g.Pk[s];
    float* __restrict__ S = g.S[s] + (size_t)p * SPART;

    const int tid = threadIdx.x, lane = tid & 63, w = tid >> 6;
    const int wm = (w >> 1) * 64, wn = (w & 1) * 64;

    f32x4 acc[4][4];
    #pragma unroll
    for (int u = 0; u < 4; ++u)
        #pragma unroll
        for (int v = 0; v < 4; ++v)
            acc[u][v] = (f32x4){0.f, 0.f, 0.f, 0.f};

    const int half = lane >> 4, r16 = lane & 15;
    const int nt = Kb >> 5;

#define GSTAGE(buf, it) do {                                                        \
        const int kq_ = kg0 + (it) * 4 + w;                                         \
        const char* ga_ = (const char*)Pk + ((size_t)kq_ * 896 + bi * 128) * 16 + lane * 16; \
        const char* gb_ = (const char*)Pk + ((size_t)kq_ * 896 + bj * 128) * 16 + lane * 16; \
        gll16(ga_,        (char*)lsA[buf] + w * 2048);                              \
        gll16(ga_ + 1024, (char*)lsA[buf] + w * 2048 + 1024);                       \
        gll16(gb_,        (char*)lsB[buf] + w * 2048);                              \
        gll16(gb_ + 1024, (char*)lsB[buf] + w * 2048 + 1024);                       \
    } while (0)

    GSTAGE(0, 0);
    asm volatile("s_waitcnt vmcnt(0)" ::: "memory");
    __builtin_amdgcn_s_barrier();

    int cur = 0;
    for (int it = 0; it < nt; ++it) {
        if (it + 1 < nt) GSTAGE(cur ^ 1, it + 1);   // prefetch under compute
        s16x8 av[4], bv[4], cv[4];
        #pragma unroll
        for (int u = 0; u < 4; ++u) {
            av[u] = *reinterpret_cast<const s16x8*>(&lsA[cur][((half * 128) + wm + 16 * u + r16) * 8]);
            union { u32x4 u4; s16x8 s8; } ub, uc;
            ub.u4 = *reinterpret_cast<const u32x4*>(&lsB[cur][((half * 128) + wn + 16 * u + r16) * 8]);
            uc.u4 = (ub.u4 >> 16) | (ub.u4 << 16);   // [hi,lo] -> [lo,hi] per dword
            bv[u] = ub.s8;
            cv[u] = uc.s8;
        }
        #pragma unroll
        for (int u = 0; u < 4; ++u)
            #pragma unroll
            for (int v = 0; v < 4; ++v) {
                acc[u][v] = __builtin_amdgcn_mfma_f32_16x16x32_bf16(av[u], bv[v], acc[u][v], 0, 0, 0);
                acc[u][v] = __builtin_amdgcn_mfma_f32_16x16x32_bf16(av[u], cv[v], acc[u][v], 0, 0, 0);
            }
        __builtin_amdgcn_sched_barrier(0);
        asm volatile("s_waitcnt vmcnt(0)" ::: "memory");
        __builtin_amdgcn_s_barrier();
        cur ^= 1;
    }
#undef GSTAGE

    const int rowb = bi * 128 + wm + (lane >> 4) * 4;
    const int colb = bj * 128 + wn + (lane & 15);
    #pragma unroll
    for (int u = 0; u < 4; ++u)
        #pragma unroll
        for (int v = 0; v < 4; ++v)
            #pragma unroll
            for (int rg = 0; rg < 4; ++rg)
                S[(size_t)(rowb + 16 * u + rg) * 896 + colb + 16 * v] = acc[u][v][rg];
}

struct SoftParams {
    const float* S[4];
    float* heat[4];
    unsigned short* Hb[4];
    int np[4];
};

__global__ __launch_bounds__(256) void softmax_kernel(SoftParams sp) {
    const int grp = (blockIdx.x * 256 + threadIdx.x) >> 4;
    const int l = threadIdx.x & 15;
    const int s = grp / 12544;
    const int rem = grp % 12544;
    const int i = rem / 784;
    const int j = (rem / 49) % 16;
    const int e = rem % 49;
    const float* __restrict__ Sb = sp.S[s];
    const int np = sp.np[s];
    const size_t rowoff = ((size_t)(i * 56 + e)) * 896 + j * 56;

    float v[4];
    #pragma unroll
    for (int t = 0; t < 4; ++t) {
        const int f = l + t * 16;
        float x = -INFINITY;
        if (f < 49) {
            x = 0.f;
            for (int p = 0; p < np; ++p) x += Sb[(size_t)p * SPART + rowoff + f];
        }
        v[t] = x;
    }
    float m = fmaxf(fmaxf(v[0], v[1]), fmaxf(v[2], v[3]));
    #pragma unroll
    for (int d = 1; d < 16; d <<= 1) m = fmaxf(m, __shfl_xor(m, d, 16));
    float ex[4], sum = 0.f;
    #pragma unroll
    for (int t = 0; t < 4; ++t) {
        const int f = l + t * 16;
        ex[t] = (f < 49) ? __expf(v[t] - m) : 0.f;
        sum += ex[t];
    }
    #pragma unroll
    for (int d = 1; d < 16; d <<= 1) sum += __shfl_xor(sum, d, 16);
    const float inv = 1.f / sum;

    float* hrow = sp.heat[s] + (((size_t)(i * 16 + j)) * 49 + e) * 49;
    unsigned short* __restrict__ Hb = sp.Hb[s];
    const size_t hbrow = (size_t)i * 56 + e;
    #pragma unroll
    for (int t = 0; t < 4; ++t) {
        const int f = l + t * 16;
        const float hv = (f < 49) ? ex[t] * inv : 0.f;
        if (f < 49) hrow[f] = hv;
        Hb[(((size_t)j * 8 + (f >> 3)) * 896 + hbrow) * 8 + (f & 7)] = f2bf(hv);
    }
}

struct PvParams {
    const unsigned short* Hb[4];
    const unsigned short* Vb[4];
    float* out[4];
    int C[4];
    int cum[5];
};

__global__ __launch_bounds__(256) void pv_kernel(PvParams pv) {
    __shared__ short lsA[8 * 128 * 8];   // Hb tile 16KB
    __shared__ short lsB[8 * 128 * 8];   // Vb tile 16KB
    int b = xcd_swz(blockIdx.x, pv.cum[4]), s = 0;   // uniform blocks: swizzle safe
    while (b >= pv.cum[s + 1]) s++;
    int rem = b - pv.cum[s];
    const int C = pv.C[s], nct = C >> 7;
    const int j = rem / (7 * nct); rem %= 7 * nct;
    const int rt = rem / nct, ct = rem % nct;   // ct-consecutive share (j,rt) Hb tile -> same-XCD L2 hits
    const int tid = threadIdx.x, lane = tid & 63, w = tid >> 6;
    const int wm = (w >> 1) * 64, wn = (w & 1) * 64;
    const unsigned short* __restrict__ Hb = pv.Hb[s];
    const unsigned short* __restrict__ Vb = pv.Vb[s];

    #pragma unroll
    for (int q = 0; q < 2; ++q) {
        const int kq = w + q * 4;
        const char* ga = (const char*)Hb + ((size_t)(j * 8 + kq) * 896 + rt * 128) * 16 + lane * 16;
        const char* gb = (const char*)Vb + ((size_t)(j * 8 + kq) * C + ct * 128) * 16 + lane * 16;
        gll16(ga,        (char*)lsA + kq * 2048);
        gll16(ga + 1024, (char*)lsA + kq * 2048 + 1024);
        gll16(gb,        (char*)lsB + kq * 2048);
        gll16(gb + 1024, (char*)lsB + kq * 2048 + 1024);
    }
    __syncthreads();   // single drain per block; no prior stores pending

    f32x4 acc[4][4];
    #pragma unroll
    for (int u = 0; u < 4; ++u)
        #pragma unroll
        for (int v = 0; v < 4; ++v)
            acc[u][v] = (f32x4){0.f, 0.f, 0.f, 0.f};

    const int r16 = lane & 15;
    #pragma unroll
    for (int ks = 0; ks < 2; ++ks) {
        const int half = ks * 4 + (lane >> 4);
        s16x8 av[4], bv[4];
        #pragma unroll
        for (int u = 0; u < 4; ++u) {
            av[u] = *reinterpret_cast<const s16x8*>(&lsA[((half * 128) + wm + 16 * u + r16) * 8]);
            bv[u] = *reinterpret_cast<const s16x8*>(&lsB[((half * 128) + wn + 16 * u + r16) * 8]);
        }
        #pragma unroll
        for (int u = 0; u < 4; ++u)
            #pragma unroll
            for (int v = 0; v < 4; ++v)
                acc[u][v] = __builtin_amdgcn_mfma_f32_16x16x32_bf16(av[u], bv[v], acc[u][v], 0, 0, 0);
    }

    #pragma unroll
    for (int u = 0; u < 4; ++u) {
        const int mb = rt * 128 + wm + 16 * u + (lane >> 4) * 4;
        #pragma unroll
        for (int rg = 0; rg < 4; ++rg) {
            const int mm = mb + rg;
            const int ii = mm / 56, e = mm % 56;
            if (e < 49) {
                float* orow = pv.out[s] + (((size_t)(ii * 16 + j)) * 49 + e) * C + ct * 128 + (lane & 15);
                #pragma unroll
                for (int v = 0; v < 4; ++v)
                    orow[wn + 16 * v] = acc[u][v][rg];
            }
        }
    }
    // stores drain asynchronously; kernel-end waits once
}

extern "C" void kernel_launch(void* const* d_in, const int* in_sizes, int n_in,
                              void* d_out, int out_size, void* d_ws, size_t ws_size,
                              hipStream_t stream) {
    const int Cs[4] = {256, 512, 1024, 2048};
    const int Hs[4] = {56, 28, 14, 7};
    const int ks[4] = {8, 4, 2, 1};
    const int Gs[4] = {1, 4, 16, 64};

    char* w0 = (char*)d_ws;
    size_t off = 0;
    unsigned short *Pk[4], *Vb[4], *Hb[4];
    for (int s = 0; s < 4; ++s) { Pk[s] = (unsigned short*)(w0 + off); off += (size_t)3584 * Cs[s]; }
    for (int s = 0; s < 4; ++s) { Vb[s] = (unsigned short*)(w0 + off); off += (size_t)2048 * Cs[s]; }
    for (int s = 0; s < 4; ++s) { Hb[s] = (unsigned short*)(w0 + off); off += (size_t)1835008; }

    int np[4] = {1, 2, 2, 4};
    {
        size_t need = off;
        for (int s = 0; s < 4; ++s) need += (size_t)np[s] * SPART * 4;
        if (ws_size < need) { np[0] = np[1] = np[2] = np[3] = 1; }
    }
    float* Sp[4];
    for (int s = 0; s < 4; ++s) { Sp[s] = (float*)(w0 + off); off += (size_t)np[s] * SPART * 4; }

    float* out = (float*)d_out;
    const size_t o1 = 0;
    const size_t o2 = o1 + (size_t)256 * 49 * 256;
    const size_t o3 = o2 + (size_t)256 * 49 * 512;
    const size_t o4 = o3 + (size_t)256 * 49 * 1024;
    const size_t h1 = o4 + (size_t)256 * 49 * 2048;
    const size_t h2 = h1 + (size_t)256 * 2401;
    const size_t h3 = h2 + (size_t)256 * 2401;
    const size_t h4 = h3 + (size_t)256 * 2401;
    float* heat[4] = {out + h1, out + h2, out + h3, out + h4};
    float* outs[4] = {out + o1, out + o2, out + o3, out + o4};

    PoolParams pp;
    pp.cum[0] = 0;
    for (int s = 0; s < 4; ++s) {
        pp.act[s] = (const float*)d_in[s];
        pp.Pk[s] = Pk[s]; pp.Vb[s] = Vb[s];
        pp.C[s] = Cs[s]; pp.H[s] = Hs[s]; pp.k[s] = ks[s]; pp.G[s] = Gs[s];
        pp.cum[s + 1] = pp.cum[s] + 16 * (Cs[s] / Gs[s]);
    }
    pool_all_kernel<<<pp.cum[4], 256, 0, stream>>>(pp);

    GramParams g;
    g.cum[0] = 0;
    for (int s = 0; s < 4; ++s) {
        g.Pk[s] = Pk[s];
        g.S[s] = Sp[s];
        g.Kblk[s] = 2 * Cs[s] / np[s];
        g.cum[s + 1] = g.cum[s] + np[s] * 49;
    }
    gram_kernel<<<g.cum[4], 256, 0, stream>>>(g);

    SoftParams sp;
    for (int s = 0; s < 4; ++s) {
        sp.S[s] = Sp[s]; sp.heat[s] = heat[s]; sp.Hb[s] = Hb[s]; sp.np[s] = np[s];
    }
    softmax_kernel<<<3136, 256, 0, stream>>>(sp);

    PvParams pv;
    pv.cum[0] = 0;
    for (int s = 0; s < 4; ++s) {
        pv.Hb[s] = Hb[s]; pv.Vb[s] = Vb[s]; pv.out[s] = outs[s]; pv.C[s] = Cs[s];
        pv.cum[s + 1] = pv.cum[s] + 16 * 7 * (Cs[s] >> 7);
    }
    pv_kernel<<<pv.cum[4], 256, 0, stream>>>(pv);
}

// Round 11
// 133.833 us; speedup vs baseline: 1.2235x; 1.0523x over previous
//
#include <hip/hip_runtime.h>
#include <hip/hip_bf16.h>
#include <cstdint>
#include <cstddef>

// B=16 images, 4 scales, pooled 7x7=49 spatial, rows padded to 56 (MROWS=896).
// R11 = R6 anchor (132us, best) byte-identical, except gram launches scales in
//       LPT order (s=3,2,1,0: long nt=32 blocks first) — pure scheduling remap.

typedef __attribute__((ext_vector_type(8))) short s16x8;
typedef __attribute__((ext_vector_type(4))) float f32x4;
typedef __attribute__((ext_vector_type(4))) uint32_t u32x4;

#define SPART 802816   // 896*896

__device__ __forceinline__ unsigned short f2bf(float x) {
    uint32_t u = __float_as_uint(x);
    uint32_t r = (u + 0x7fff + ((u >> 16) & 1)) >> 16;
    return (unsigned short)r;
}
__device__ __forceinline__ float bf2f(unsigned short b) {
    return __uint_as_float(((uint32_t)b) << 16);
}
__device__ __forceinline__ void gll16(const void* g, void* l) {
    __builtin_amdgcn_global_load_lds(
        (const __attribute__((address_space(1))) uint32_t*)g,
        (__attribute__((address_space(3))) uint32_t*)l, 16, 0, 0);
}

struct PoolParams {
    const float* act[4];
    unsigned short* Pk[4];
    unsigned short* Vb[4];
    int C[4], H[4], k[4], G[4], cum[5];
};

__global__ __launch_bounds__(256) void pool_all_kernel(PoolParams pp) {
    __shared__ alignas(16) float plane[3136];
    int b = blockIdx.x, s = 0;
    while (b >= pp.cum[s + 1]) s++;
    const int rem = b - pp.cum[s];
    const int C = pp.C[s], H = pp.H[s], k = pp.k[s], G = pp.G[s];
    const int HW = H * H;
    const int nblk_c = C / G;
    const int i  = rem / nblk_c;
    const int c0 = (rem % nblk_c) * G;
    unsigned short* __restrict__ Pk = pp.Pk[s];
    unsigned short* __restrict__ Vb = pp.Vb[s];

    const float4* src4 = reinterpret_cast<const float4*>(pp.act[s] + ((size_t)i * C + c0) * HW);
    float4* plane4 = reinterpret_cast<float4*>(plane);
    for (int idx = threadIdx.x; idx < (G * HW) >> 2; idx += 256)
        plane4[idx] = src4[idx];
    __syncthreads();
    for (int idx = threadIdx.x; idx < G * 49; idx += 256) {
        const int e = idx / G, g = idx % G;
        const int eh = e / 7, ew = e % 7;
        const float* ppl = plane + g * HW + (eh * k) * H + ew * k;
        float m = -INFINITY;
        for (int dy = 0; dy < k; ++dy)
            for (int dx = 0; dx < k; ++dx)
                m = fmaxf(m, ppl[dy * H + dx]);
        const int c = c0 + g;
        const unsigned short hb = f2bf(m);
        const unsigned short lb = f2bf(m - bf2f(hb));
        const size_t pk = (((size_t)(c >> 2) * 896) + (size_t)i * 56 + e) * 8 + ((c & 3) * 2);
        *reinterpret_cast<uint32_t*>(&Pk[pk]) = (uint32_t)hb | ((uint32_t)lb << 16);
        const size_t vb = (((size_t)i * 8 + (e >> 3)) * C + c) * 8 + (e & 7);
        Vb[vb] = hb;
    }
    for (int idx = threadIdx.x; idx < 7 * G; idx += 256) {
        const int e = 49 + idx / G, g = idx % G, c = c0 + g;
        const size_t pk = (((size_t)(c >> 2) * 896) + (size_t)i * 56 + e) * 8 + ((c & 3) * 2);
        *reinterpret_cast<uint32_t*>(&Pk[pk]) = 0;
    }
    for (int idx = threadIdx.x; idx < 15 * G; idx += 256) {
        const int e = 49 + idx / G, g = idx % G, c = c0 + g;
        const size_t vb = (((size_t)i * 8 + (e >> 3)) * C + c) * 8 + (e & 7);
        Vb[vb] = 0;
    }
}

struct GramParams {
    const unsigned short* Pk[4];
    float* S[4];
    int Kblk[4];   // k' elements per block per pass (=2C/np), indexed by SLOT
    int sord[4];   // slot -> scale (LPT: long scales first)
    int cum[5];
};

__global__ __launch_bounds__(256) void gram_kernel(GramParams g) {
    __shared__ short lsA[2][4096];
    __shared__ short lsB[2][4096];
    int b = blockIdx.x, q = 0;
    while (b >= g.cum[q + 1]) q++;
    const int s = g.sord[q];
    const int rem = b - g.cum[q];
    const int p = rem / 49, t = rem % 49;
    const int bi = t / 7, bj = t % 7;
    const int Kb = g.Kblk[q];
    const int kg0 = p * (Kb >> 3);
    const unsigned short* __restrict__ Pk = g.Pk[s];
    float* __restrict__ S = g.S[s] + (size_t)p * SPART;

    const int tid = threadIdx.x, lane = tid & 63, w = tid >> 6;
    const int wm = (w >> 1) * 64, wn = (w & 1) * 64;

    f32x4 acc[4][4];
    #pragma unroll
    for (int u = 0; u < 4; ++u)
        #pragma unroll
        for (int v = 0; v < 4; ++v)
            acc[u][v] = (f32x4){0.f, 0.f, 0.f, 0.f};

    const int half = lane >> 4, r16 = lane & 15;
    const int nt = Kb >> 5;

#define GSTAGE(buf, it) do {                                                        \
        const int kq_ = kg0 + (it) * 4 + w;                                         \
        const char* ga_ = (const char*)Pk + ((size_t)kq_ * 896 + bi * 128) * 16 + lane * 16; \
        const char* gb_ = (const char*)Pk + ((size_t)kq_ * 896 + bj * 128) * 16 + lane * 16; \
        gll16(ga_,        (char*)lsA[buf] + w * 2048);                              \
        gll16(ga_ + 1024, (char*)lsA[buf] + w * 2048 + 1024);                       \
        gll16(gb_,        (char*)lsB[buf] + w * 2048);                              \
        gll16(gb_ + 1024, (char*)lsB[buf] + w * 2048 + 1024);                       \
    } while (0)

    GSTAGE(0, 0);
    asm volatile("s_waitcnt vmcnt(0)" ::: "memory");
    __builtin_amdgcn_s_barrier();

    int cur = 0;
    for (int it = 0; it < nt; ++it) {
        if (it + 1 < nt) GSTAGE(cur ^ 1, it + 1);   // prefetch under compute
        s16x8 av[4], bv[4], cv[4];
        #pragma unroll
        for (int u = 0; u < 4; ++u) {
            av[u] = *reinterpret_cast<const s16x8*>(&lsA[cur][((half * 128) + wm + 16 * u + r16) * 8]);
            union { u32x4 u4; s16x8 s8; } ub, uc;
            ub.u4 = *reinterpret_cast<const u32x4*>(&lsB[cur][((half * 128) + wn + 16 * u + r16) * 8]);
            uc.u4 = (ub.u4 >> 16) | (ub.u4 << 16);   // [hi,lo] -> [lo,hi] per dword
            bv[u] = ub.s8;
            cv[u] = uc.s8;
        }
        #pragma unroll
        for (int u = 0; u < 4; ++u)
            #pragma unroll
            for (int v = 0; v < 4; ++v) {
                acc[u][v] = __builtin_amdgcn_mfma_f32_16x16x32_bf16(av[u], bv[v], acc[u][v], 0, 0, 0);
                acc[u][v] = __builtin_amdgcn_mfma_f32_16x16x32_bf16(av[u], cv[v], acc[u][v], 0, 0, 0);
            }
        __builtin_amdgcn_sched_barrier(0);
        asm volatile("s_waitcnt vmcnt(0)" ::: "memory");
        __builtin_amdgcn_s_barrier();
        cur ^= 1;
    }
#undef GSTAGE

    const int rowb = bi * 128 + wm + (lane >> 4) * 4;
    const int colb = bj * 128 + wn + (lane & 15);
    #pragma unroll
    for (int u = 0; u < 4; ++u)
        #pragma unroll
        for (int v = 0; v < 4; ++v)
            #pragma unroll
            for (int rg = 0; rg < 4; ++rg)
                S[(size_t)(rowb + 16 * u + rg) * 896 + colb + 16 * v] = acc[u][v][rg];
}

struct SoftParams {
    const float* S[4];
    float* heat[4];
    unsigned short* Hb[4];
    int np[4];
};

__global__ __launch_bounds__(256) void softmax_kernel(SoftParams sp) {
    const int grp = (blockIdx.x * 256 + threadIdx.x) >> 4;
    const int l = threadIdx.x & 15;
    const int s = grp / 12544;
    const int rem = grp % 12544;
    const int i = rem / 784;
    const int j = (rem / 49) % 16;
    const int e = rem % 49;
    const float* __restrict__ Sb = sp.S[s];
    const int np = sp.np[s];
    const size_t rowoff = ((size_t)(i * 56 + e)) * 896 + j * 56;

    float v[4];
    #pragma unroll
    for (int t = 0; t < 4; ++t) {
        const int f = l + t * 16;
        float x = -INFINITY;
        if (f < 49) {
            x = 0.f;
            for (int p = 0; p < np; ++p) x += Sb[(size_t)p * SPART + rowoff + f];
        }
        v[t] = x;
    }
    float m = fmaxf(fmaxf(v[0], v[1]), fmaxf(v[2], v[3]));
    #pragma unroll
    for (int d = 1; d < 16; d <<= 1) m = fmaxf(m, __shfl_xor(m, d, 16));
    float ex[4], sum = 0.f;
    #pragma unroll
    for (int t = 0; t < 4; ++t) {
        const int f = l + t * 16;
        ex[t] = (f < 49) ? __expf(v[t] - m) : 0.f;
        sum += ex[t];
    }
    #pragma unroll
    for (int d = 1; d < 16; d <<= 1) sum += __shfl_xor(sum, d, 16);
    const float inv = 1.f / sum;

    float* hrow = sp.heat[s] + (((size_t)(i * 16 + j)) * 49 + e) * 49;
    unsigned short* __restrict__ Hb = sp.Hb[s];
    const size_t hbrow = (size_t)i * 56 + e;
    #pragma unroll
    for (int t = 0; t < 4; ++t) {
        const int f = l + t * 16;
        const float hv = (f < 49) ? ex[t] * inv : 0.f;
        if (f < 49) hrow[f] = hv;
        Hb[(((size_t)j * 8 + (f >> 3)) * 896 + hbrow) * 8 + (f & 7)] = f2bf(hv);
    }
}

struct PvParams {
    const unsigned short* Hb[4];
    const unsigned short* Vb[4];
    float* out[4];
    int C[4];
    int cum[5];
};

__global__ __launch_bounds__(256) void pv_kernel(PvParams pv) {
    __shared__ short lsA[8 * 128 * 8];   // Hb tile 16KB
    __shared__ short lsB[8 * 128 * 8];   // Vb tile 16KB
    int b = blockIdx.x, s = 0;
    while (b >= pv.cum[s + 1]) s++;
    int rem = b - pv.cum[s];
    const int C = pv.C[s], nct = C >> 7;
    const int j = rem / (7 * nct); rem %= 7 * nct;
    const int rt = rem / nct, ct = rem % nct;
    const int tid = threadIdx.x, lane = tid & 63, w = tid >> 6;
    const int wm = (w >> 1) * 64, wn = (w & 1) * 64;
    const unsigned short* __restrict__ Hb = pv.Hb[s];
    const unsigned short* __restrict__ Vb = pv.Vb[s];

    #pragma unroll
    for (int q = 0; q < 2; ++q) {
        const int kq = w + q * 4;
        const char* ga = (const char*)Hb + ((size_t)(j * 8 + kq) * 896 + rt * 128) * 16 + lane * 16;
        const char* gb = (const char*)Vb + ((size_t)(j * 8 + kq) * C + ct * 128) * 16 + lane * 16;
        gll16(ga,        (char*)lsA + kq * 2048);
        gll16(ga + 1024, (char*)lsA + kq * 2048 + 1024);
        gll16(gb,        (char*)lsB + kq * 2048);
        gll16(gb + 1024, (char*)lsB + kq * 2048 + 1024);
    }
    __syncthreads();   // single drain per block; no prior stores pending

    f32x4 acc[4][4];
    #pragma unroll
    for (int u = 0; u < 4; ++u)
        #pragma unroll
        for (int v = 0; v < 4; ++v)
            acc[u][v] = (f32x4){0.f, 0.f, 0.f, 0.f};

    const int r16 = lane & 15;
    #pragma unroll
    for (int ks = 0; ks < 2; ++ks) {
        const int half = ks * 4 + (lane >> 4);
        s16x8 av[4], bv[4];
        #pragma unroll
        for (int u = 0; u < 4; ++u) {
            av[u] = *reinterpret_cast<const s16x8*>(&lsA[((half * 128) + wm + 16 * u + r16) * 8]);
            bv[u] = *reinterpret_cast<const s16x8*>(&lsB[((half * 128) + wn + 16 * u + r16) * 8]);
        }
        #pragma unroll
        for (int u = 0; u < 4; ++u)
            #pragma unroll
            for (int v = 0; v < 4; ++v)
                acc[u][v] = __builtin_amdgcn_mfma_f32_16x16x32_bf16(av[u], bv[v], acc[u][v], 0, 0, 0);
    }

    #pragma unroll
    for (int u = 0; u < 4; ++u) {
        const int mb = rt * 128 + wm + 16 * u + (lane >> 4) * 4;
        #pragma unroll
        for (int rg = 0; rg < 4; ++rg) {
            const int mm = mb + rg;
            const int ii = mm / 56, e = mm % 56;
            if (e < 49) {
                float* orow = pv.out[s] + (((size_t)(ii * 16 + j)) * 49 + e) * C + ct * 128 + (lane & 15);
                #pragma unroll
                for (int v = 0; v < 4; ++v)
                    orow[wn + 16 * v] = acc[u][v][rg];
            }
        }
    }
    // stores drain asynchronously; kernel-end waits once
}

extern "C" void kernel_launch(void* const* d_in, const int* in_sizes, int n_in,
                              void* d_out, int out_size, void* d_ws, size_t ws_size,
                              hipStream_t stream) {
    const int Cs[4] = {256, 512, 1024, 2048};
    const int Hs[4] = {56, 28, 14, 7};
    const int ks[4] = {8, 4, 2, 1};
    const int Gs[4] = {1, 4, 16, 64};

    char* w0 = (char*)d_ws;
    size_t off = 0;
    unsigned short *Pk[4], *Vb[4], *Hb[4];
    for (int s = 0; s < 4; ++s) { Pk[s] = (unsigned short*)(w0 + off); off += (size_t)3584 * Cs[s]; }
    for (int s = 0; s < 4; ++s) { Vb[s] = (unsigned short*)(w0 + off); off += (size_t)2048 * Cs[s]; }
    for (int s = 0; s < 4; ++s) { Hb[s] = (unsigned short*)(w0 + off); off += (size_t)1835008; }

    int np[4] = {1, 2, 2, 4};
    {
        size_t need = off;
        for (int s = 0; s < 4; ++s) need += (size_t)np[s] * SPART * 4;
        if (ws_size < need) { np[0] = np[1] = np[2] = np[3] = 1; }
    }
    float* Sp[4];
    for (int s = 0; s < 4; ++s) { Sp[s] = (float*)(w0 + off); off += (size_t)np[s] * SPART * 4; }

    float* out = (float*)d_out;
    const size_t o1 = 0;
    const size_t o2 = o1 + (size_t)256 * 49 * 256;
    const size_t o3 = o2 + (size_t)256 * 49 * 512;
    const size_t o4 = o3 + (size_t)256 * 49 * 1024;
    const size_t h1 = o4 + (size_t)256 * 49 * 2048;
    const size_t h2 = h1 + (size_t)256 * 2401;
    const size_t h3 = h2 + (size_t)256 * 2401;
    const size_t h4 = h3 + (size_t)256 * 2401;
    float* heat[4] = {out + h1, out + h2, out + h3, out + h4};
    float* outs[4] = {out + o1, out + o2, out + o3, out + o4};

    PoolParams pp;
    pp.cum[0] = 0;
    for (int s = 0; s < 4; ++s) {
        pp.act[s] = (const float*)d_in[s];
        pp.Pk[s] = Pk[s]; pp.Vb[s] = Vb[s];
        pp.C[s] = Cs[s]; pp.H[s] = Hs[s]; pp.k[s] = ks[s]; pp.G[s] = Gs[s];
        pp.cum[s + 1] = pp.cum[s] + 16 * (Cs[s] / Gs[s]);
    }
    pool_all_kernel<<<pp.cum[4], 256, 0, stream>>>(pp);

    GramParams g;
    // LPT: launch long (nt=32) scales 3,2 first, then 1,0
    const int sordv[4] = {3, 2, 1, 0};
    g.cum[0] = 0;
    for (int q = 0; q < 4; ++q) {
        const int s = sordv[q];
        g.sord[q] = s;
        g.Pk[s] = Pk[s];
        g.S[s] = Sp[s];
        g.Kblk[q] = 2 * Cs[s] / np[s];
        g.cum[q + 1] = g.cum[q] + np[s] * 49;
    }
    gram_kernel<<<g.cum[4], 256, 0, stream>>>(g);

    SoftParams sp;
    for (int s = 0; s < 4; ++s) {
        sp.S[s] = Sp[s]; sp.heat[s] = heat[s]; sp.Hb[s] = Hb[s]; sp.np[s] = np[s];
    }
    softmax_kernel<<<3136, 256, 0, stream>>>(sp);

    PvParams pv;
    pv.cum[0] = 0;
    for (int s = 0; s < 4; ++s) {
        pv.Hb[s] = Hb[s]; pv.Vb[s] = Vb[s]; pv.out[s] = outs[s]; pv.C[s] = Cs[s];
        pv.cum[s + 1] = pv.cum[s] + 16 * 7 * (Cs[s] >> 7);
    }
    pv_kernel<<<pv.cum[4], 256, 0, stream>>>(pv);
}